// Round 2
// baseline (136.953 us; speedup 1.0000x reference)
//
#include <hip/hip_runtime.h>

#define IN_F 1024
#define OUT_F 1024
#define NNZ 16384

typedef _Float16 f16;
typedef _Float16 f16x4 __attribute__((ext_vector_type(4)));
typedef _Float16 f16x8 __attribute__((ext_vector_type(8)));
typedef float f32x4 __attribute__((ext_vector_type(4)));
typedef unsigned short ushort8 __attribute__((ext_vector_type(8)));

// ---------------------------------------------------------------------------
// Workspace layout: S = staged W_eff (f16, 2 MiB) at offset 0; mode flag (int)
// at offset 2 MiB.
//
// Staged W layout (S):
//   tile t = nt*16 + kt   (nt in [0,8): 128 output rows; kt in [0,16): 64 k)
//   1024 slots per tile, 8 halfs (16 B) per slot.
//   slot s: r = s>>3 (row in tile), bb = s&7 (swizzled 16B block)
//   content = W_eff[nt*128 + r][kt*64 + ((bb ^ (r&7))<<3) .. +8]
// GEMM stages slot s linearly into LDS (global_load_lds, linear dest), and
// fragment reads apply the same XOR -> conflict-free, data correct (G21).
// ---------------------------------------------------------------------------

// Detect how the harness delivered the fp16 weights: 0=f32 upcast, 1=bf16, 2=f16.
//  - f16 native: fp32-read exponent = (u16_hi>>7)&0xFF ~ 18-25 -> |v| < 2^-100.
//  - bf16: fp32-read ~ weight magnitude (>1e-6); all u16-as-bf16 exps <= ~124.
//  - f32 (from fp16): low u16 = [m2 m1 m0]<<13 -> bf16-exp field in {0,64,128,192};
//    192 >= 140 occurs w.p. 1-(3/4)^1024 ~ 1.  bf16 case never reaches 140.
__global__ void detect_mode(const unsigned short* __restrict__ w, int* __restrict__ mode) {
  __shared__ float smax[256];
  __shared__ int semax[256];
  int t = threadIdx.x;
  const float* wf = (const float*)w;
  float m32 = fabsf(wf[t]);
  m32 = fmaxf(m32, fabsf(wf[t + 256]));
  int e8 = 0;
#pragma unroll
  for (int j = 0; j < 8; ++j) {
    unsigned short u = w[t * 8 + j];
    int e = (u >> 7) & 0xFF;
    e8 = e > e8 ? e : e8;
  }
  smax[t] = m32; semax[t] = e8;
  __syncthreads();
  for (int s = 128; s > 0; s >>= 1) {
    if (t < s) {
      smax[t] = fmaxf(smax[t], smax[t + s]);
      semax[t] = semax[t] > semax[t + s] ? semax[t] : semax[t + s];
    }
    __syncthreads();
  }
  if (t == 0) {
    int m;
    if (!(smax[0] > 1e-6f)) m = 2;        // native f16
    else if (semax[0] >= 140) m = 0;      // f32 (upcast from fp16)
    else m = 1;                           // bf16
    *mode = m;
  }
}

__device__ __forceinline__ float load_w(const void* base, size_t i, int mode) {
  if (mode == 0) return ((const float*)base)[i];
  if (mode == 1) {
    unsigned int u = (unsigned int)((const unsigned short*)base)[i] << 16;
    return __uint_as_float(u);
  }
  return (float)((const f16*)base)[i];
}

__global__ void prep_base(const void* __restrict__ base, f16* __restrict__ S,
                          const int* __restrict__ modep) {
  int mode = *modep;
  int g = blockIdx.x * 256 + threadIdx.x;   // slot id, total 131072
  int tile = g >> 10;
  int s = g & 1023;
  int nt = tile >> 4, kt = tile & 15;
  int r = s >> 3, bb = s & 7;
  int n = nt * 128 + r;
  int k = kt * 64 + ((bb ^ (r & 7)) << 3);
  size_t off = (size_t)n * IN_F + k;
  f16x8 h;
  if (mode == 0) {
    const float* b = (const float*)base + off;
    float4 v0 = *reinterpret_cast<const float4*>(b);
    float4 v1 = *reinterpret_cast<const float4*>(b + 4);
    h = (f16x8){(f16)v0.x, (f16)v0.y, (f16)v0.z, (f16)v0.w,
                (f16)v1.x, (f16)v1.y, (f16)v1.z, (f16)v1.w};
  } else if (mode == 1) {
    ushort8 u = *reinterpret_cast<const ushort8*>((const unsigned short*)base + off);
#pragma unroll
    for (int j = 0; j < 8; ++j)
      h[j] = (f16)__uint_as_float((unsigned int)u[j] << 16);
  } else {
    h = *reinterpret_cast<const f16x8*>((const f16*)base + off);
  }
  *reinterpret_cast<f16x8*>(S + (size_t)g * 8) = h;
}

__global__ void prep_scatter(const void* __restrict__ base,
                             const void* __restrict__ vals,
                             const int* __restrict__ idx,
                             const float* __restrict__ alpha,
                             f16* __restrict__ S,
                             const int* __restrict__ modep) {
  int mode = *modep;
  int i = blockIdx.x * 256 + threadIdx.x;
  if (i >= NNZ) return;
  int id = idx[i];
  int n = id >> 10, k = id & 1023;
  float v = load_w(base, id, mode) + alpha[0] * load_w(vals, i, mode);
  int nt = n >> 7, r = n & 127;
  int kt = k >> 6, kk = k & 63;
  int b = kk >> 3, e = kk & 7;
  int slot = (r << 3) | (b ^ (r & 7));
  size_t pos = ((size_t)((nt * 16 + kt) * 1024 + slot)) * 8 + (size_t)e;
  S[pos] = (f16)v;
}

// ---------------------------------------------------------------------------
// GEMM: C[M][1024] = X[M][1024](fp32) * W_eff^T   (f16 MFMA, fp32 accum)
// BM=BN=128, BK=64, 256 threads = 4 waves (2x2), wave tile 64x64.
// ---------------------------------------------------------------------------
__global__ void __launch_bounds__(256) gemm_kernel(const float* __restrict__ X,
                                                   const f16* __restrict__ S,
                                                   float* __restrict__ C) {
  __shared__ f16 sX[128 * 64];
  __shared__ f16 sW[128 * 64];

  // bijective XCD swizzle: group the 8 n-tiles of each m-panel on one XCD
  int bidx = blockIdx.x;
  int q = gridDim.x >> 3;                 // gridDim.x % 8 == 0
  int wg = (bidx & 7) * q + (bidx >> 3);
  int mt = wg >> 3, nt = wg & 7;

  int t = threadIdx.x;
  int lane = t & 63;
  int w = t >> 6;
  int wm = w >> 1, wn = w & 1;
  int lr = lane & 15;        // row within 16x16 fragment
  int lk = lane >> 4;        // k-block (0..3) / C row group

  const float* Xg = X + (size_t)mt * 128 * IN_F;
  const f16* Sg = S + (size_t)nt * 16 * 1024 * 8;

  f32x4 acc[4][4];
#pragma unroll
  for (int i = 0; i < 4; ++i)
#pragma unroll
    for (int j = 0; j < 4; ++j)
      acc[i][j] = (f32x4){0.f, 0.f, 0.f, 0.f};

  for (int kt = 0; kt < 16; ++kt) {
    // ---- stage X: 128x64 fp32 -> f16, XOR-swizzled 16B blocks ----
#pragma unroll
    for (int j = 0; j < 8; ++j) {
      int f = t + j * 256;             // float4 id in tile, 2048 total
      int r = f >> 4, c4 = f & 15;
      float4 v = *reinterpret_cast<const float4*>(Xg + (size_t)r * IN_F + kt * 64 + c4 * 4);
      f16x4 h = {(f16)v.x, (f16)v.y, (f16)v.z, (f16)v.w};
      int hi = r * 64 + ((((c4 >> 1) ^ (r & 7)) << 3) + ((c4 & 1) << 2));
      *reinterpret_cast<f16x4*>(&sX[hi]) = h;
    }
    // ---- stage W: pre-swizzled source, linear LDS dest, width-16 ----
    const f16* St = Sg + (size_t)kt * 1024 * 8;
#pragma unroll
    for (int c = 0; c < 4; ++c) {
      int slot = c * 256 + t;          // wave-uniform base + lane*16
      __builtin_amdgcn_global_load_lds(
          (const __attribute__((address_space(1))) void*)(St + (size_t)slot * 8),
          (__attribute__((address_space(3))) void*)(&sW[slot * 8]),
          16, 0, 0);
    }
    __syncthreads();   // drains vmcnt/lgkmcnt

    // ---- compute: 2 k-steps x 16 MFMA ----
#pragma unroll
    for (int ks = 0; ks < 2; ++ks) {
      f16x8 a[4], b[4];
#pragma unroll
      for (int mf = 0; mf < 4; ++mf) {
        int r = wm * 64 + mf * 16 + lr;
        int blk = (ks * 4 + lk) ^ (lr & 7);
        a[mf] = *reinterpret_cast<const f16x8*>(&sX[r * 64 + blk * 8]);
      }
#pragma unroll
      for (int nf = 0; nf < 4; ++nf) {
        int r = wn * 64 + nf * 16 + lr;
        int blk = (ks * 4 + lk) ^ (lr & 7);
        b[nf] = *reinterpret_cast<const f16x8*>(&sW[r * 64 + blk * 8]);
      }
#pragma unroll
      for (int mf = 0; mf < 4; ++mf)
#pragma unroll
        for (int nf = 0; nf < 4; ++nf)
          acc[mf][nf] = __builtin_amdgcn_mfma_f32_16x16x32_f16(a[mf], b[nf], acc[mf][nf], 0, 0, 0);
    }
    __syncthreads();   // protect LDS before next stage
  }

  // ---- epilogue: D layout col = lane&15, row = (lane>>4)*4 + reg ----
  float* Cw = C + (size_t)(mt * 128 + wm * 64 + lk * 4) * OUT_F + nt * 128 + wn * 64 + lr;
#pragma unroll
  for (int mf = 0; mf < 4; ++mf)
#pragma unroll
    for (int nf = 0; nf < 4; ++nf)
#pragma unroll
      for (int g = 0; g < 4; ++g)
        Cw[(size_t)(mf * 16 + g) * OUT_F + nf * 16] = acc[mf][nf][g];
}

extern "C" void kernel_launch(void* const* d_in, const int* in_sizes, int n_in,
                              void* d_out, int out_size, void* d_ws, size_t ws_size,
                              hipStream_t stream) {
  const float* X = (const float*)d_in[0];
  const void* base = d_in[1];
  const void* vals = d_in[2];
  const int* idx = (const int*)d_in[3];
  const float* alpha = (const float*)d_in[4];
  float* out = (float*)d_out;
  f16* S = (f16*)d_ws;                                    // 2 MiB staged W
  int* modep = (int*)((char*)d_ws + 2 * 1024 * 1024);     // mode flag

  int M = in_sizes[0] / IN_F;              // 32768
  int mtiles = M / 128;                    // 256

  detect_mode<<<dim3(1), dim3(256), 0, stream>>>((const unsigned short*)base, modep);
  prep_base<<<dim3((OUT_F * IN_F / 8) / 256), dim3(256), 0, stream>>>(base, S, modep);
  prep_scatter<<<dim3((NNZ + 255) / 256), dim3(256), 0, stream>>>(base, vals, idx, alpha, S, modep);
  gemm_kernel<<<dim3(mtiles * 8), dim3(256), 0, stream>>>(X, S, out);
}

// Round 3
// 132.229 us; speedup vs baseline: 1.0357x; 1.0357x over previous
//
#include <hip/hip_runtime.h>

#define IN_F 1024
#define OUT_F 1024
#define NNZ 16384

typedef _Float16 f16;
typedef _Float16 f16x4 __attribute__((ext_vector_type(4)));
typedef _Float16 f16x8 __attribute__((ext_vector_type(8)));
typedef float f32x4 __attribute__((ext_vector_type(4)));
typedef unsigned short ushort8 __attribute__((ext_vector_type(8)));

// ---------------------------------------------------------------------------
// Workspace: S = staged W_eff (f16, 2 MiB) @0; mode flag (int) @2MiB.
// Staged W layout: tile t = nt*16+kt; slot s = r*8+bb (r row-in-tile, bb
// swizzled 16B block); content = W_eff[nt*128+r][kt*64 + ((bb^(r&7))<<3)..+8].
// GEMM stages slots linearly (global_load_lds) and reads with the same XOR.
// ---------------------------------------------------------------------------

__global__ void detect_mode(const unsigned short* __restrict__ w, int* __restrict__ mode) {
  __shared__ float smax[256];
  __shared__ int semax[256];
  int t = threadIdx.x;
  const float* wf = (const float*)w;
  float m32 = fabsf(wf[t]);
  m32 = fmaxf(m32, fabsf(wf[t + 256]));
  int e8 = 0;
#pragma unroll
  for (int j = 0; j < 8; ++j) {
    unsigned short u = w[t * 8 + j];
    int e = (u >> 7) & 0xFF;
    e8 = e > e8 ? e : e8;
  }
  smax[t] = m32; semax[t] = e8;
  __syncthreads();
  for (int s = 128; s > 0; s >>= 1) {
    if (t < s) {
      smax[t] = fmaxf(smax[t], smax[t + s]);
      semax[t] = semax[t] > semax[t + s] ? semax[t] : semax[t + s];
    }
    __syncthreads();
  }
  if (t == 0) {
    int m;
    if (!(smax[0] > 1e-6f)) m = 2;        // native f16
    else if (semax[0] >= 140) m = 0;      // f32 (upcast from fp16)
    else m = 1;                           // bf16
    *mode = m;
  }
}

__device__ __forceinline__ float load_w(const void* base, size_t i, int mode) {
  if (mode == 0) return ((const float*)base)[i];
  if (mode == 1) {
    unsigned int u = (unsigned int)((const unsigned short*)base)[i] << 16;
    return __uint_as_float(u);
  }
  return (float)((const f16*)base)[i];
}

__global__ void prep_base(const void* __restrict__ base, f16* __restrict__ S,
                          const int* __restrict__ modep) {
  int mode = *modep;
  int g = blockIdx.x * 256 + threadIdx.x;
  int tile = g >> 10;
  int s = g & 1023;
  int nt = tile >> 4, kt = tile & 15;
  int r = s >> 3, bb = s & 7;
  int n = nt * 128 + r;
  int k = kt * 64 + ((bb ^ (r & 7)) << 3);
  size_t off = (size_t)n * IN_F + k;
  f16x8 h;
  if (mode == 0) {
    const float* b = (const float*)base + off;
    float4 v0 = *reinterpret_cast<const float4*>(b);
    float4 v1 = *reinterpret_cast<const float4*>(b + 4);
    h = (f16x8){(f16)v0.x, (f16)v0.y, (f16)v0.z, (f16)v0.w,
                (f16)v1.x, (f16)v1.y, (f16)v1.z, (f16)v1.w};
  } else if (mode == 1) {
    ushort8 u = *reinterpret_cast<const ushort8*>((const unsigned short*)base + off);
#pragma unroll
    for (int j = 0; j < 8; ++j)
      h[j] = (f16)__uint_as_float((unsigned int)u[j] << 16);
  } else {
    h = *reinterpret_cast<const f16x8*>((const f16*)base + off);
  }
  *reinterpret_cast<f16x8*>(S + (size_t)g * 8) = h;
}

__global__ void prep_scatter(const void* __restrict__ base,
                             const void* __restrict__ vals,
                             const int* __restrict__ idx,
                             const float* __restrict__ alpha,
                             f16* __restrict__ S,
                             const int* __restrict__ modep) {
  int mode = *modep;
  int i = blockIdx.x * 256 + threadIdx.x;
  if (i >= NNZ) return;
  int id = idx[i];
  int n = id >> 10, k = id & 1023;
  float v = load_w(base, id, mode) + alpha[0] * load_w(vals, i, mode);
  int nt = n >> 7, r = n & 127;
  int kt = k >> 6, kk = k & 63;
  int b = kk >> 3, e = kk & 7;
  int slot = (r << 3) | (b ^ (r & 7));
  size_t pos = ((size_t)((nt * 16 + kt) * 1024 + slot)) * 8 + (size_t)e;
  S[pos] = (f16)v;
}

// ---------------------------------------------------------------------------
// GEMM: C[M][1024] = X(fp32) * W_eff^T, f16 MFMA / fp32 accum.
// BM=BN=128, BK=64, 256 threads (4 waves 2x2). Pipelined: raw s_barrier +
// counted vmcnt (T3/T4-lite), W via global_load_lds 2-iter-deep, X reg-staged
// issue-early (T14), double-buffered LDS, setprio around MFMA (T5).
// ---------------------------------------------------------------------------

#define ISSUE_W(P, KT) do {                                                    \
    const f16* St_ = Sg + (size_t)(KT) * 8192;                                 \
    _Pragma("unroll")                                                          \
    for (int c_ = 0; c_ < 4; ++c_) {                                           \
      int slot_ = c_ * 256 + t;                                                \
      __builtin_amdgcn_global_load_lds(                                        \
          (const __attribute__((address_space(1))) void*)(St_ + (size_t)slot_ * 8), \
          (__attribute__((address_space(3))) void*)(&sW[P][slot_ * 8]),        \
          16, 0, 0);                                                           \
    }                                                                          \
  } while (0)

#define ISSUE_A(KT) do {                                                       \
    int ko_ = (KT) * 64;                                                       \
    _Pragma("unroll")                                                          \
    for (int j_ = 0; j_ < 8; ++j_)                                             \
      ar[j_] = *reinterpret_cast<const float4*>(Xg + goff[j_] + ko_);          \
  } while (0)

#define STEP(P, KT, PREFA, PREFW, LAST) do {                                   \
    if (LAST) asm volatile("s_waitcnt vmcnt(0)" ::: "memory");                 \
    else      asm volatile("s_waitcnt vmcnt(4)" ::: "memory");                 \
    _Pragma("unroll")                                                          \
    for (int j_ = 0; j_ < 8; ++j_) {                                           \
      float4 v_ = ar[j_];                                                      \
      f16x4 h_ = {(f16)v_.x, (f16)v_.y, (f16)v_.z, (f16)v_.w};                 \
      *reinterpret_cast<f16x4*>(&sX[P][hio[j_]]) = h_;                         \
    }                                                                          \
    asm volatile("s_waitcnt lgkmcnt(0)" ::: "memory");                         \
    __builtin_amdgcn_s_barrier();                                              \
    __builtin_amdgcn_sched_barrier(0);                                         \
    if (PREFA) { ISSUE_A((KT) + 1); }                                          \
    __builtin_amdgcn_s_setprio(1);                                             \
    _Pragma("unroll")                                                          \
    for (int ks_ = 0; ks_ < 2; ++ks_) {                                        \
      f16x8 a_[4], b_[4];                                                      \
      _Pragma("unroll")                                                        \
      for (int mf_ = 0; mf_ < 4; ++mf_) {                                      \
        int r_ = wm * 64 + mf_ * 16 + lr;                                      \
        int blk_ = (ks_ * 4 + lk) ^ (lr & 7);                                  \
        a_[mf_] = *reinterpret_cast<const f16x8*>(&sX[P][r_ * 64 + blk_ * 8]); \
      }                                                                        \
      _Pragma("unroll")                                                        \
      for (int nf_ = 0; nf_ < 4; ++nf_) {                                      \
        int r_ = wn * 64 + nf_ * 16 + lr;                                      \
        int blk_ = (ks_ * 4 + lk) ^ (lr & 7);                                  \
        b_[nf_] = *reinterpret_cast<const f16x8*>(&sW[P][r_ * 64 + blk_ * 8]); \
      }                                                                        \
      _Pragma("unroll")                                                        \
      for (int mf_ = 0; mf_ < 4; ++mf_)                                        \
        _Pragma("unroll")                                                      \
        for (int nf_ = 0; nf_ < 4; ++nf_)                                      \
          acc[mf_][nf_] = __builtin_amdgcn_mfma_f32_16x16x32_f16(              \
              a_[mf_], b_[nf_], acc[mf_][nf_], 0, 0, 0);                       \
    }                                                                          \
    __builtin_amdgcn_s_setprio(0);                                             \
    __builtin_amdgcn_s_barrier();                                              \
    __builtin_amdgcn_sched_barrier(0);                                         \
    if (PREFW) { ISSUE_W(P, (KT) + 2); }                                       \
  } while (0)

__global__ void __launch_bounds__(256) gemm_kernel(const float* __restrict__ X,
                                                   const f16* __restrict__ S,
                                                   float* __restrict__ C) {
  __shared__ f16 sX[2][8192];
  __shared__ f16 sW[2][8192];

  // bijective XCD swizzle: group the 8 n-tiles of each m-panel on one XCD
  int bidx = blockIdx.x;
  int q = gridDim.x >> 3;                 // gridDim.x % 8 == 0
  int wg = (bidx & 7) * q + (bidx >> 3);
  int mt = wg >> 3, nt = wg & 7;

  int t = threadIdx.x;
  int lane = t & 63;
  int w = t >> 6;
  int wm = w >> 1, wn = w & 1;
  int lr = lane & 15;        // row within 16x16 fragment
  int lk = lane >> 4;        // k-block / C row group

  const float* Xg = X + (size_t)mt * 128 * IN_F;
  const f16* Sg = S + (size_t)nt * 16 * 8192;

  // per-thread staging geometry (constant across K-iters)
  int goff[8], hio[8];
#pragma unroll
  for (int j = 0; j < 8; ++j) {
    int f = t + j * 256;             // float4 id in 128x64 tile
    int r = f >> 4, c4 = f & 15;
    goff[j] = r * IN_F + c4 * 4;
    hio[j] = r * 64 + ((((c4 >> 1) ^ (r & 7)) << 3) + ((c4 & 1) << 2));
  }

  float4 ar[8];                      // single in-flight X reg-stage set
  f32x4 acc[4][4];
#pragma unroll
  for (int i = 0; i < 4; ++i)
#pragma unroll
    for (int j = 0; j < 4; ++j)
      acc[i][j] = (f32x4){0.f, 0.f, 0.f, 0.f};

  // prologue: W(0)->buf0, A(0)->regs, W(1)->buf1   (16 VMEM in flight)
  ISSUE_W(0, 0);
  ISSUE_A(0);
  ISSUE_W(1, 1);

  // main loop: kt = 0..13 fully pipelined
  for (int i = 0; i < 7; ++i) {
    STEP(0, 2 * i,     true, true, false);
    STEP(1, 2 * i + 1, true, true, false);
  }
  // tail: kt=14 (prefetch A15 only), kt=15 (drain)
  STEP(0, 14, true,  false, false);
  STEP(1, 15, false, false, true);

  // epilogue: D layout col = lane&15, row = (lane>>4)*4 + reg
  float* Cw = C + (size_t)(mt * 128 + wm * 64 + lk * 4) * OUT_F + nt * 128 + wn * 64 + lr;
#pragma unroll
  for (int mf = 0; mf < 4; ++mf)
#pragma unroll
    for (int nf = 0; nf < 4; ++nf)
#pragma unroll
      for (int g = 0; g < 4; ++g)
        Cw[(size_t)(mf * 16 + g) * OUT_F + nf * 16] = acc[mf][nf][g];
}

extern "C" void kernel_launch(void* const* d_in, const int* in_sizes, int n_in,
                              void* d_out, int out_size, void* d_ws, size_t ws_size,
                              hipStream_t stream) {
  const float* X = (const float*)d_in[0];
  const void* base = d_in[1];
  const void* vals = d_in[2];
  const int* idx = (const int*)d_in[3];
  const float* alpha = (const float*)d_in[4];
  float* out = (float*)d_out;
  f16* S = (f16*)d_ws;                                    // 2 MiB staged W
  int* modep = (int*)((char*)d_ws + 2 * 1024 * 1024);     // mode flag

  int M = in_sizes[0] / IN_F;              // 32768
  int mtiles = M / 128;                    // 256

  detect_mode<<<dim3(1), dim3(256), 0, stream>>>((const unsigned short*)base, modep);
  prep_base<<<dim3((OUT_F * IN_F / 8) / 256), dim3(256), 0, stream>>>(base, S, modep);
  prep_scatter<<<dim3((NNZ + 255) / 256), dim3(256), 0, stream>>>(base, vals, idx, alpha, S, modep);
  gemm_kernel<<<dim3(mtiles * 8), dim3(256), 0, stream>>>(X, S, out);
}

// Round 4
// 131.384 us; speedup vs baseline: 1.0424x; 1.0064x over previous
//
#include <hip/hip_runtime.h>

#define IN_F 1024
#define OUT_F 1024
#define NNZ 16384

typedef _Float16 f16;
typedef _Float16 f16x4 __attribute__((ext_vector_type(4)));
typedef _Float16 f16x8 __attribute__((ext_vector_type(8)));
typedef float f32x4 __attribute__((ext_vector_type(4)));
typedef unsigned short ushort8 __attribute__((ext_vector_type(8)));

// ---------------------------------------------------------------------------
// Workspace: S = staged W_eff (f16, 2 MiB) @0; mode flag (int) @2MiB.
// Staged W layout: tile t = nt*16+kt; slot s = r*8+bb (r row-in-tile, bb
// swizzled 16B block); content = W_eff[nt*128+r][kt*64 + ((bb^(r&7))<<3)..+8].
// GEMM stages slots linearly (global_load_lds) and reads with the same XOR.
// ---------------------------------------------------------------------------

__global__ void detect_mode(const unsigned short* __restrict__ w, int* __restrict__ mode) {
  __shared__ float smax[256];
  __shared__ int semax[256];
  int t = threadIdx.x;
  const float* wf = (const float*)w;
  float m32 = fabsf(wf[t]);
  m32 = fmaxf(m32, fabsf(wf[t + 256]));
  int e8 = 0;
#pragma unroll
  for (int j = 0; j < 8; ++j) {
    unsigned short u = w[t * 8 + j];
    int e = (u >> 7) & 0xFF;
    e8 = e > e8 ? e : e8;
  }
  smax[t] = m32; semax[t] = e8;
  __syncthreads();
  for (int s = 128; s > 0; s >>= 1) {
    if (t < s) {
      smax[t] = fmaxf(smax[t], smax[t + s]);
      semax[t] = semax[t] > semax[t + s] ? semax[t] : semax[t + s];
    }
    __syncthreads();
  }
  if (t == 0) {
    int m;
    if (!(smax[0] > 1e-6f)) m = 2;        // native f16
    else if (semax[0] >= 140) m = 0;      // f32 (upcast from fp16)
    else m = 1;                           // bf16
    *mode = m;
  }
}

__device__ __forceinline__ float load_w(const void* base, size_t i, int mode) {
  if (mode == 0) return ((const float*)base)[i];
  if (mode == 1) {
    unsigned int u = (unsigned int)((const unsigned short*)base)[i] << 16;
    return __uint_as_float(u);
  }
  return (float)((const f16*)base)[i];
}

__global__ void prep_base(const void* __restrict__ base, f16* __restrict__ S,
                          const int* __restrict__ modep) {
  int mode = *modep;
  int g = blockIdx.x * 256 + threadIdx.x;
  int tile = g >> 10;
  int s = g & 1023;
  int nt = tile >> 4, kt = tile & 15;
  int r = s >> 3, bb = s & 7;
  int n = nt * 128 + r;
  int k = kt * 64 + ((bb ^ (r & 7)) << 3);
  size_t off = (size_t)n * IN_F + k;
  f16x8 h;
  if (mode == 0) {
    const float* b = (const float*)base + off;
    float4 v0 = *reinterpret_cast<const float4*>(b);
    float4 v1 = *reinterpret_cast<const float4*>(b + 4);
    h = (f16x8){(f16)v0.x, (f16)v0.y, (f16)v0.z, (f16)v0.w,
                (f16)v1.x, (f16)v1.y, (f16)v1.z, (f16)v1.w};
  } else if (mode == 1) {
    ushort8 u = *reinterpret_cast<const ushort8*>((const unsigned short*)base + off);
#pragma unroll
    for (int j = 0; j < 8; ++j)
      h[j] = (f16)__uint_as_float((unsigned int)u[j] << 16);
  } else {
    h = *reinterpret_cast<const f16x8*>((const f16*)base + off);
  }
  *reinterpret_cast<f16x8*>(S + (size_t)g * 8) = h;
}

__global__ void prep_scatter(const void* __restrict__ base,
                             const void* __restrict__ vals,
                             const int* __restrict__ idx,
                             const float* __restrict__ alpha,
                             f16* __restrict__ S,
                             const int* __restrict__ modep) {
  int mode = *modep;
  int i = blockIdx.x * 256 + threadIdx.x;
  if (i >= NNZ) return;
  int id = idx[i];
  int n = id >> 10, k = id & 1023;
  float v = load_w(base, id, mode) + alpha[0] * load_w(vals, i, mode);
  int nt = n >> 7, r = n & 127;
  int kt = k >> 6, kk = k & 63;
  int b = kk >> 3, e = kk & 7;
  int slot = (r << 3) | (b ^ (r & 7));
  size_t pos = ((size_t)((nt * 16 + kt) * 1024 + slot)) * 8 + (size_t)e;
  S[pos] = (f16)v;
}

// ---------------------------------------------------------------------------
// GEMM: C[M][1024] = X(fp32) * W_eff^T, f16 MFMA / fp32 accum.
// BM=BN=128, BK=64, 256 threads (4 waves 2x2). DISTANCE-2 pipeline:
// A(KT+2) and W(KT+2) are issued during STEP(KT) -> ~2 full steps of flight
// (>= HBM latency ~900cy). Steady-state wait vmcnt(12) (= drain A(KT)+W(KT),
// keep KT+1/KT+2 in flight). Raw s_barrier, setprio around MFMA.
// ---------------------------------------------------------------------------

#define ISSUE_W(P, KT) do {                                                    \
    const f16* St_ = Sg + (size_t)(KT) * 8192;                                 \
    _Pragma("unroll")                                                          \
    for (int c_ = 0; c_ < 4; ++c_) {                                           \
      int slot_ = c_ * 256 + t;                                                \
      __builtin_amdgcn_global_load_lds(                                        \
          (const __attribute__((address_space(1))) void*)(St_ + (size_t)slot_ * 8), \
          (__attribute__((address_space(3))) void*)(&sW[P][slot_ * 8]),        \
          16, 0, 0);                                                           \
    }                                                                          \
  } while (0)

#define ISSUE_A(R, KT) do {                                                    \
    int ko_ = (KT) * 64;                                                       \
    _Pragma("unroll")                                                          \
    for (int j_ = 0; j_ < 8; ++j_)                                             \
      ar##R[j_] = *reinterpret_cast<const float4*>(Xg + goff[j_] + ko_);       \
  } while (0)

// One K-step. P = LDS buffer parity (KT&1), R = A-reg set parity (KT&1).
// PREF: issue A(KT+2)/W(KT+2).  VM: vmcnt immediate at top.
#define STEP(P, R, KT, PREF, VM) do {                                          \
    asm volatile("s_waitcnt vmcnt(" #VM ")" ::: "memory");                     \
    _Pragma("unroll")                                                          \
    for (int j_ = 0; j_ < 8; ++j_) {                                           \
      float4 v_ = ar##R[j_];                                                   \
      f16x4 h_ = {(f16)v_.x, (f16)v_.y, (f16)v_.z, (f16)v_.w};                 \
      *reinterpret_cast<f16x4*>(&sX[P][hio[j_]]) = h_;                         \
    }                                                                          \
    asm volatile("s_waitcnt lgkmcnt(0)" ::: "memory");                         \
    __builtin_amdgcn_s_barrier();                                              \
    __builtin_amdgcn_sched_barrier(0);                                         \
    if (PREF) { ISSUE_A(R, (KT) + 2); }                                        \
    __builtin_amdgcn_sched_barrier(0);                                         \
    __builtin_amdgcn_s_setprio(1);                                             \
    _Pragma("unroll")                                                          \
    for (int ks_ = 0; ks_ < 2; ++ks_) {                                        \
      f16x8 a_[4], b_[4];                                                      \
      _Pragma("unroll")                                                        \
      for (int mf_ = 0; mf_ < 4; ++mf_) {                                      \
        int r_ = wm * 64 + mf_ * 16 + lr;                                      \
        int blk_ = (ks_ * 4 + lk) ^ (lr & 7);                                  \
        a_[mf_] = *reinterpret_cast<const f16x8*>(&sX[P][r_ * 64 + blk_ * 8]); \
      }                                                                        \
      _Pragma("unroll")                                                        \
      for (int nf_ = 0; nf_ < 4; ++nf_) {                                      \
        int r_ = wn * 64 + nf_ * 16 + lr;                                      \
        int blk_ = (ks_ * 4 + lk) ^ (lr & 7);                                  \
        b_[nf_] = *reinterpret_cast<const f16x8*>(&sW[P][r_ * 64 + blk_ * 8]); \
      }                                                                        \
      _Pragma("unroll")                                                        \
      for (int mf_ = 0; mf_ < 4; ++mf_)                                        \
        _Pragma("unroll")                                                      \
        for (int nf_ = 0; nf_ < 4; ++nf_)                                      \
          acc[mf_][nf_] = __builtin_amdgcn_mfma_f32_16x16x32_f16(              \
              a_[mf_], b_[nf_], acc[mf_][nf_], 0, 0, 0);                       \
    }                                                                          \
    __builtin_amdgcn_s_setprio(0);                                             \
    __builtin_amdgcn_s_barrier();                                              \
    __builtin_amdgcn_sched_barrier(0);                                         \
    if (PREF) { ISSUE_W(P, (KT) + 2); }                                        \
    __builtin_amdgcn_sched_barrier(0);                                         \
  } while (0)

__global__ void __launch_bounds__(256) gemm_kernel(const float* __restrict__ X,
                                                   const f16* __restrict__ S,
                                                   float* __restrict__ C) {
  __shared__ f16 sX[2][8192];
  __shared__ f16 sW[2][8192];

  // bijective XCD swizzle: group the 8 n-tiles of each m-panel on one XCD
  int bidx = blockIdx.x;
  int q = gridDim.x >> 3;                 // gridDim.x % 8 == 0
  int wg = (bidx & 7) * q + (bidx >> 3);
  int mt = wg >> 3, nt = wg & 7;

  int t = threadIdx.x;
  int lane = t & 63;
  int w = t >> 6;
  int wm = w >> 1, wn = w & 1;
  int lr = lane & 15;        // row within 16x16 fragment
  int lk = lane >> 4;        // k-block / C row group

  const float* Xg = X + (size_t)mt * 128 * IN_F;
  const f16* Sg = S + (size_t)nt * 16 * 8192;

  // per-thread staging geometry (constant across K-iters)
  int goff[8], hio[8];
#pragma unroll
  for (int j = 0; j < 8; ++j) {
    int f = t + j * 256;             // float4 id in 128x64 tile
    int r = f >> 4, c4 = f & 15;
    goff[j] = r * IN_F + c4 * 4;
    hio[j] = r * 64 + ((((c4 >> 1) ^ (r & 7)) << 3) + ((c4 & 1) << 2));
  }

  float4 ar0[8], ar1[8];             // two in-flight X reg-stage sets
  f32x4 acc[4][4];
#pragma unroll
  for (int i = 0; i < 4; ++i)
#pragma unroll
    for (int j = 0; j < 4; ++j)
      acc[i][j] = (f32x4){0.f, 0.f, 0.f, 0.f};

  // prologue: W0, A0, W1, A1  (24 VMEM in flight; oldest = W0,A0)
  ISSUE_W(0, 0);
  ISSUE_A(0, 0);
  ISSUE_W(1, 1);
  ISSUE_A(1, 1);

  // main loop: kt = 0..13 fully pipelined (prefetch kt+2)
  for (int i = 0; i < 7; ++i) {
    STEP(0, 0, 2 * i,     true, 12);
    STEP(1, 1, 2 * i + 1, true, 12);
  }
  // tail: kt=14 (A15/W15 still in flight), kt=15 (drain)
  STEP(0, 0, 14, false, 12);
  STEP(1, 1, 15, false, 0);

  // epilogue: D layout col = lane&15, row = (lane>>4)*4 + reg
  float* Cw = C + (size_t)(mt * 128 + wm * 64 + lk * 4) * OUT_F + nt * 128 + wn * 64 + lr;
#pragma unroll
  for (int mf = 0; mf < 4; ++mf)
#pragma unroll
    for (int nf = 0; nf < 4; ++nf)
#pragma unroll
      for (int g = 0; g < 4; ++g)
        Cw[(size_t)(mf * 16 + g) * OUT_F + nf * 16] = acc[mf][nf][g];
}

extern "C" void kernel_launch(void* const* d_in, const int* in_sizes, int n_in,
                              void* d_out, int out_size, void* d_ws, size_t ws_size,
                              hipStream_t stream) {
  const float* X = (const float*)d_in[0];
  const void* base = d_in[1];
  const void* vals = d_in[2];
  const int* idx = (const int*)d_in[3];
  const float* alpha = (const float*)d_in[4];
  float* out = (float*)d_out;
  f16* S = (f16*)d_ws;                                    // 2 MiB staged W
  int* modep = (int*)((char*)d_ws + 2 * 1024 * 1024);     // mode flag

  int M = in_sizes[0] / IN_F;              // 32768
  int mtiles = M / 128;                    // 256

  detect_mode<<<dim3(1), dim3(256), 0, stream>>>((const unsigned short*)base, modep);
  prep_base<<<dim3((OUT_F * IN_F / 8) / 256), dim3(256), 0, stream>>>(base, S, modep);
  prep_scatter<<<dim3((NNZ + 255) / 256), dim3(256), 0, stream>>>(base, vals, idx, alpha, S, modep);
  gemm_kernel<<<dim3(mtiles * 8), dim3(256), 0, stream>>>(X, S, out);
}